// Round 1
// baseline (2190.946 us; speedup 1.0000x reference)
//
#include <hip/hip_runtime.h>
#include <hip/hip_bf16.h>
#include <math.h>

#define N_NODES 50000
#define N_EDGES 800000
#define HEADS 4
#define HC_MAX 256   // H*C for layers 0..3

// ---------------------------------------------------------------------------
// CSR construction: deg histogram -> scan -> scatter (dst-sorted edge list)
// ---------------------------------------------------------------------------

__global__ void init_deg_kernel(int* __restrict__ deg) {
    int i = blockIdx.x * blockDim.x + threadIdx.x;
    if (i < N_NODES) deg[i] = 1;  // self-loop
}

__global__ void hist_kernel(const int* __restrict__ dst, int* __restrict__ deg) {
    int i = blockIdx.x * blockDim.x + threadIdx.x;
    if (i < N_EDGES) atomicAdd(&deg[dst[i]], 1);
}

// Single-block scan over N_NODES degrees. deg may alias cursor (we write
// cursor[i] only after reading deg[i] within the same thread's chunk).
__global__ __launch_bounds__(1024) void scan_kernel(const int* __restrict__ deg,
                                                    int* __restrict__ rowptr,
                                                    int* __restrict__ cursor) {
    __shared__ int sums[1024];
    const int t = threadIdx.x;
    const int CHUNK = (N_NODES + 1023) / 1024;  // 49
    int begin = t * CHUNK;
    int end = begin + CHUNK; if (end > N_NODES) end = N_NODES;
    if (begin > N_NODES) begin = N_NODES;

    int s = 0;
    for (int i = begin; i < end; ++i) s += deg[i];
    sums[t] = s;
    __syncthreads();
    for (int off = 1; off < 1024; off <<= 1) {
        int v = (t >= off) ? sums[t - off] : 0;
        __syncthreads();
        sums[t] += v;
        __syncthreads();
    }
    int run = (t == 0) ? 0 : sums[t - 1];
    for (int i = begin; i < end; ++i) {
        int d = deg[i];          // read BEFORE aliased write
        rowptr[i] = run;
        cursor[i] = run;
        run += d;
    }
    if (t == 1023) rowptr[N_NODES] = run;
}

__global__ void scatter_kernel(const int* __restrict__ src, const int* __restrict__ dst,
                               int* __restrict__ cursor, int* __restrict__ col) {
    int i = blockIdx.x * blockDim.x + threadIdx.x;
    if (i < N_EDGES) {
        int d = dst[i];
        int pos = atomicAdd(&cursor[d], 1);
        col[pos] = src[i];
    } else if (i < N_EDGES + N_NODES) {
        int n = i - N_EDGES;
        int pos = atomicAdd(&cursor[n], 1);
        col[pos] = n;            // self loop
    }
}

// ---------------------------------------------------------------------------
// f32 GEMM: C[M x Ncols] = A[M x K] * B[K x Ncols], all row-major.
// Block tile 64 x 256, 256 threads, 8x8 register blocking, BK=32 LDS staging.
// Ncols < 256 handled by zero-padding B tile and guarding stores.
// ---------------------------------------------------------------------------

__global__ __launch_bounds__(256) void gemm_kernel(const float* __restrict__ A,
                                                   const float* __restrict__ B,
                                                   float* __restrict__ C,
                                                   int M, int K, int Ncols) {
    constexpr int BK = 32;
    __shared__ float Xs[BK][64];    // transposed A tile: Xs[k][row]
    __shared__ float Ws[BK][256];   // B tile

    const int tid = threadIdx.x;
    const int block_row = blockIdx.x * 64;
    const int tr = tid >> 5;   // 0..7  (row group of 8)
    const int tc = tid & 31;   // 0..31 (col group of 8)

    float acc[8][8];
#pragma unroll
    for (int i = 0; i < 8; ++i)
#pragma unroll
        for (int j = 0; j < 8; ++j) acc[i][j] = 0.f;

    for (int k0 = 0; k0 < K; k0 += BK) {
        // A tile: 64 rows x BK cols -> transposed into Xs. 512 float4 / 256 thr = 2.
#pragma unroll
        for (int l = tid; l < 64 * BK / 4; l += 256) {
            int r = l / (BK / 4);
            int kc4 = (l % (BK / 4)) * 4;
            float4 v = make_float4(0.f, 0.f, 0.f, 0.f);
            int gr = block_row + r;
            if (gr < M) v = *reinterpret_cast<const float4*>(&A[(size_t)gr * K + k0 + kc4]);
            Xs[kc4 + 0][r] = v.x;
            Xs[kc4 + 1][r] = v.y;
            Xs[kc4 + 2][r] = v.z;
            Xs[kc4 + 3][r] = v.w;
        }
        // B tile: BK rows x 256 cols (zero-pad cols >= Ncols). 2048 float4 / 256 = 8.
#pragma unroll
        for (int l = tid; l < BK * 256 / 4; l += 256) {
            int kr = l / 64;
            int c4 = (l % 64) * 4;
            float4 v = make_float4(0.f, 0.f, 0.f, 0.f);
            if (c4 < Ncols) v = *reinterpret_cast<const float4*>(&B[(size_t)(k0 + kr) * Ncols + c4]);
            *reinterpret_cast<float4*>(&Ws[kr][c4]) = v;
        }
        __syncthreads();

#pragma unroll
        for (int kk = 0; kk < BK; ++kk) {
            float xv[8], wv[8];
            *reinterpret_cast<float4*>(&xv[0]) = *reinterpret_cast<const float4*>(&Xs[kk][tr * 8]);
            *reinterpret_cast<float4*>(&xv[4]) = *reinterpret_cast<const float4*>(&Xs[kk][tr * 8 + 4]);
            *reinterpret_cast<float4*>(&wv[0]) = *reinterpret_cast<const float4*>(&Ws[kk][tc * 8]);
            *reinterpret_cast<float4*>(&wv[4]) = *reinterpret_cast<const float4*>(&Ws[kk][tc * 8 + 4]);
#pragma unroll
            for (int i = 0; i < 8; ++i)
#pragma unroll
                for (int j = 0; j < 8; ++j) acc[i][j] += xv[i] * wv[j];
        }
        __syncthreads();
    }

#pragma unroll
    for (int i = 0; i < 8; ++i) {
        int gr = block_row + tr * 8 + i;
        if (gr >= M) continue;
#pragma unroll
        for (int j = 0; j < 8; j += 4) {
            int c = tc * 8 + j;
            if (c < Ncols)
                *reinterpret_cast<float4*>(&C[(size_t)gr * Ncols + c]) =
                    *reinterpret_cast<const float4*>(&acc[i][j]);
        }
    }
}

// ---------------------------------------------------------------------------
// Attention coefficients: asn[n,h] = <h[n,h,:], a_s[h,:]>, adn likewise.
// ---------------------------------------------------------------------------

__global__ void attn_coef_kernel(const float* __restrict__ h,
                                 const float* __restrict__ a_s,
                                 const float* __restrict__ a_d,
                                 float* __restrict__ asn, float* __restrict__ adn,
                                 int CH) {
    int t = blockIdx.x * blockDim.x + threadIdx.x;
    if (t >= N_NODES * HEADS) return;
    int n = t >> 2;
    int hd = t & 3;
    const float* hp = h + (size_t)n * HEADS * CH + hd * CH;
    const float* sp = a_s + hd * CH;
    const float* dp = a_d + hd * CH;
    float s1 = 0.f, s2 = 0.f;
    for (int c = 0; c < CH; c += 2) {
        float2 hv = *reinterpret_cast<const float2*>(&hp[c]);
        float2 av = *reinterpret_cast<const float2*>(&sp[c]);
        float2 dv = *reinterpret_cast<const float2*>(&dp[c]);
        s1 += hv.x * av.x + hv.y * av.y;
        s2 += hv.x * dv.x + hv.y * dv.y;
    }
    asn[t] = s1;
    adn[t] = s2;
}

// ---------------------------------------------------------------------------
// Fused online-softmax aggregation. One block (256 thr) per node; wave = head;
// lane = channel. out[n,h,c] = relu( sum_e alpha_e * h[src_e,h,c] + b[h,c] ).
// ---------------------------------------------------------------------------

template <int CH>
__global__ __launch_bounds__(256) void aggregate_kernel(
        const float* __restrict__ h, const float* __restrict__ asn,
        const float* __restrict__ adn, const int* __restrict__ rowptr,
        const int* __restrict__ col, const float* __restrict__ bias,
        float* __restrict__ out) {
    const int n = blockIdx.x;
    const int hd = threadIdx.x >> 6;
    const int lane = threadIdx.x & 63;

    const int start = rowptr[n];
    const int end = rowptr[n + 1];
    const float adv = adn[n * HEADS + hd];

    float m = -INFINITY, s = 0.f, acc = 0.f;
    for (int e = start; e < end; ++e) {
        int src = col[e];  // wave-uniform
        float ev = asn[src * HEADS + hd] + adv;
        ev = (ev > 0.f) ? ev : 0.2f * ev;   // leaky_relu(0.2)
        float mn = fmaxf(m, ev);
        float scale = __expf(m - mn);       // first iter: exp(-inf)=0
        float p = __expf(ev - mn);
        float hv = (lane < CH) ? h[(size_t)src * HEADS * CH + hd * CH + lane] : 0.f;
        s = s * scale + p;
        acc = acc * scale + p * hv;
        m = mn;
    }
    if (lane < CH) {
        float v = acc / (s + 1e-16f) + bias[hd * CH + lane];
        out[(size_t)n * HEADS * CH + hd * CH + lane] = fmaxf(v, 0.f);
    }
}

// ---------------------------------------------------------------------------

extern "C" void kernel_launch(void* const* d_in, const int* in_sizes, int n_in,
                              void* d_out, int out_size, void* d_ws, size_t ws_size,
                              hipStream_t stream) {
    const float* x_in = (const float*)d_in[0];
    const int* ei = (const int*)d_in[1];
    const int* src = ei;
    const int* dst = ei + N_EDGES;

    const float *W[5], *AS[5], *AD[5], *BI[5];
    for (int l = 0; l < 5; ++l) {
        W[l]  = (const float*)d_in[2 + l * 4 + 0];
        AS[l] = (const float*)d_in[2 + l * 4 + 1];
        AD[l] = (const float*)d_in[2 + l * 4 + 2];
        BI[l] = (const float*)d_in[2 + l * 4 + 3];
    }

    // workspace carve-up
    float* X    = (float*)d_ws;                 // N x 256
    float* Hb   = X + (size_t)N_NODES * 256;    // N x 256
    float* asn  = Hb + (size_t)N_NODES * 256;   // N x 4
    float* adn  = asn + (size_t)N_NODES * HEADS;
    int* rowptr = (int*)(adn + (size_t)N_NODES * HEADS);  // N+1
    int* cursor = rowptr + (N_NODES + 1);                 // N
    int* col    = cursor + N_NODES;                       // E + N

    // --- CSR build (recomputed every call; deterministic work) ---
    init_deg_kernel<<<(N_NODES + 255) / 256, 256, 0, stream>>>(cursor);
    hist_kernel<<<(N_EDGES + 255) / 256, 256, 0, stream>>>(dst, cursor);
    scan_kernel<<<1, 1024, 0, stream>>>(cursor, rowptr, cursor);
    scatter_kernel<<<(N_EDGES + N_NODES + 255) / 256, 256, 0, stream>>>(src, dst, cursor, col);

    // --- 5 GAT layers ---
    const float* cur = x_in;
    int K = 64;
    const int gemm_blocks = (N_NODES + 63) / 64;
    for (int l = 0; l < 5; ++l) {
        const int NC = (l == 4) ? 40 : 256;   // H * dout
        const int CH = (l == 4) ? 10 : 64;    // dout per head
        gemm_kernel<<<gemm_blocks, 256, 0, stream>>>(cur, W[l], Hb, N_NODES, K, NC);
        attn_coef_kernel<<<(N_NODES * HEADS + 255) / 256, 256, 0, stream>>>(
            Hb, AS[l], AD[l], asn, adn, CH);
        float* outp = (l == 4) ? (float*)d_out : X;
        if (CH == 64) {
            aggregate_kernel<64><<<N_NODES, 256, 0, stream>>>(Hb, asn, adn, rowptr, col, BI[l], outp);
        } else {
            aggregate_kernel<10><<<N_NODES, 256, 0, stream>>>(Hb, asn, adn, rowptr, col, BI[l], outp);
        }
        cur = X;
        K = 256;
    }
    (void)in_sizes; (void)n_in; (void)out_size; (void)ws_size;
}

// Round 2
// 1556.945 us; speedup vs baseline: 1.4072x; 1.4072x over previous
//
#include <hip/hip_runtime.h>
#include <hip/hip_bf16.h>
#include <math.h>

#define N_NODES 50000
#define N_EDGES 800000
#define HEADS 4

// ---------------------------------------------------------------------------
// CSR construction: deg histogram -> scan -> scatter (dst-sorted edge list)
// ---------------------------------------------------------------------------

__global__ void init_deg_kernel(int* __restrict__ deg) {
    int i = blockIdx.x * blockDim.x + threadIdx.x;
    if (i < N_NODES) deg[i] = 1;  // self-loop
}

__global__ void hist_kernel(const int* __restrict__ dst, int* __restrict__ deg) {
    int i = blockIdx.x * blockDim.x + threadIdx.x;
    if (i < N_EDGES) atomicAdd(&deg[dst[i]], 1);
}

// Single-block scan over N_NODES degrees. deg may alias cursor.
__global__ __launch_bounds__(1024) void scan_kernel(const int* __restrict__ deg,
                                                    int* __restrict__ rowptr,
                                                    int* __restrict__ cursor) {
    __shared__ int sums[1024];
    const int t = threadIdx.x;
    const int CHUNK = (N_NODES + 1023) / 1024;  // 49
    int begin = t * CHUNK;
    int end = begin + CHUNK; if (end > N_NODES) end = N_NODES;
    if (begin > N_NODES) begin = N_NODES;

    int s = 0;
    for (int i = begin; i < end; ++i) s += deg[i];
    sums[t] = s;
    __syncthreads();
    for (int off = 1; off < 1024; off <<= 1) {
        int v = (t >= off) ? sums[t - off] : 0;
        __syncthreads();
        sums[t] += v;
        __syncthreads();
    }
    int run = (t == 0) ? 0 : sums[t - 1];
    for (int i = begin; i < end; ++i) {
        int d = deg[i];          // read BEFORE aliased write
        rowptr[i] = run;
        cursor[i] = run;
        run += d;
    }
    if (t == 1023) rowptr[N_NODES] = run;
}

__global__ void scatter_kernel(const int* __restrict__ src, const int* __restrict__ dst,
                               int* __restrict__ cursor, int* __restrict__ col) {
    int i = blockIdx.x * blockDim.x + threadIdx.x;
    if (i < N_EDGES) {
        int d = dst[i];
        int pos = atomicAdd(&cursor[d], 1);
        col[pos] = src[i];
    } else if (i < N_EDGES + N_NODES) {
        int n = i - N_EDGES;
        int pos = atomicAdd(&cursor[n], 1);
        col[pos] = n;            // self loop
    }
}

// ---------------------------------------------------------------------------
// f32 GEMM: C[M x Ncols] = A[M x K] * B[K x Ncols], row-major.
// Block tile 64 x 256, 256 threads, 8x8 register blocking (cols split as
// {tc*4..+3} U {128+tc*4..+3} for conflict-free 16B-stride LDS reads),
// BK=32. B tile staged via global_load_lds when Ncols==256 (linear layout).
// ---------------------------------------------------------------------------

__global__ __launch_bounds__(256) void gemm_kernel(const float* __restrict__ A,
                                                   const float* __restrict__ B,
                                                   float* __restrict__ C,
                                                   int M, int K, int Ncols) {
    constexpr int BK = 32;
    __shared__ float Xs[BK][64];    // transposed A tile: Xs[k][row]
    __shared__ float Ws[BK][256];   // B tile (linear)

    const int tid = threadIdx.x;
    const int block_row = blockIdx.x * 64;
    const int tr = tid >> 5;   // 0..7  (row group of 8)
    const int tc = tid & 31;   // 0..31 (two col groups of 4)

    float acc[8][8];
#pragma unroll
    for (int i = 0; i < 8; ++i)
#pragma unroll
        for (int j = 0; j < 8; ++j) acc[i][j] = 0.f;

    const bool linB = (Ncols == 256);

    for (int k0 = 0; k0 < K; k0 += BK) {
        // A tile: 64 rows x BK cols -> transposed into Xs.
#pragma unroll
        for (int l = tid; l < 64 * BK / 4; l += 256) {
            int r = l / (BK / 4);
            int kc4 = (l % (BK / 4)) * 4;
            float4 v = make_float4(0.f, 0.f, 0.f, 0.f);
            int gr = block_row + r;
            if (gr < M) v = *reinterpret_cast<const float4*>(&A[gr * K + k0 + kc4]);
            Xs[kc4 + 0][r] = v.x;
            Xs[kc4 + 1][r] = v.y;
            Xs[kc4 + 2][r] = v.z;
            Xs[kc4 + 3][r] = v.w;
        }
        // B tile
        if (linB) {
            // tile is a contiguous 32KB slab of B starting at k0*256 floats
#pragma unroll
            for (int it = 0; it < 8; ++it) {
                const float* gsrc = B + (k0 << 8) + (it << 10) + (tid << 2);
                float* ldst = &Ws[0][0] + (it << 10) + ((tid & ~63) << 2);
                __builtin_amdgcn_global_load_lds(
                    (const __attribute__((address_space(1))) void*)gsrc,
                    (__attribute__((address_space(3))) void*)ldst,
                    16, 0, 0);
            }
        } else {
#pragma unroll
            for (int l = tid; l < BK * 256 / 4; l += 256) {
                int kr = l / 64;
                int c4 = (l % 64) * 4;
                float4 v = make_float4(0.f, 0.f, 0.f, 0.f);
                if (c4 < Ncols) v = *reinterpret_cast<const float4*>(&B[(k0 + kr) * Ncols + c4]);
                *reinterpret_cast<float4*>(&Ws[kr][c4]) = v;
            }
        }
        __syncthreads();

#pragma unroll
        for (int kk = 0; kk < BK; ++kk) {
            float xv[8], wv[8];
            *reinterpret_cast<float4*>(&xv[0]) = *reinterpret_cast<const float4*>(&Xs[kk][tr * 8]);
            *reinterpret_cast<float4*>(&xv[4]) = *reinterpret_cast<const float4*>(&Xs[kk][tr * 8 + 4]);
            *reinterpret_cast<float4*>(&wv[0]) = *reinterpret_cast<const float4*>(&Ws[kk][tc * 4]);
            *reinterpret_cast<float4*>(&wv[4]) = *reinterpret_cast<const float4*>(&Ws[kk][128 + tc * 4]);
#pragma unroll
            for (int i = 0; i < 8; ++i)
#pragma unroll
                for (int j = 0; j < 8; ++j) acc[i][j] += xv[i] * wv[j];
        }
        __syncthreads();
    }

#pragma unroll
    for (int i = 0; i < 8; ++i) {
        int gr = block_row + tr * 8 + i;
        if (gr >= M) continue;
        int c1 = tc * 4;
        int c2 = 128 + tc * 4;
        if (c1 < Ncols)
            *reinterpret_cast<float4*>(&C[gr * Ncols + c1]) =
                *reinterpret_cast<const float4*>(&acc[i][0]);
        if (c2 < Ncols)
            *reinterpret_cast<float4*>(&C[gr * Ncols + c2]) =
                *reinterpret_cast<const float4*>(&acc[i][4]);
    }
}

// ---------------------------------------------------------------------------
// Attention coefficients: asn[n,h] = <h[n,h,:], a_s[h,:]>, adn likewise.
// ---------------------------------------------------------------------------

__global__ void attn_coef_kernel(const float* __restrict__ h,
                                 const float* __restrict__ a_s,
                                 const float* __restrict__ a_d,
                                 float* __restrict__ asn, float* __restrict__ adn,
                                 int CH) {
    int t = blockIdx.x * blockDim.x + threadIdx.x;
    if (t >= N_NODES * HEADS) return;
    int n = t >> 2;
    int hd = t & 3;
    const float* hp = h + n * HEADS * CH + hd * CH;
    const float* sp = a_s + hd * CH;
    const float* dp = a_d + hd * CH;
    float s1 = 0.f, s2 = 0.f;
    if ((CH & 3) == 0) {
        for (int c = 0; c < CH; c += 4) {
            float4 hv = *reinterpret_cast<const float4*>(&hp[c]);
            float4 av = *reinterpret_cast<const float4*>(&sp[c]);
            float4 dv = *reinterpret_cast<const float4*>(&dp[c]);
            s1 += hv.x * av.x + hv.y * av.y + hv.z * av.z + hv.w * av.w;
            s2 += hv.x * dv.x + hv.y * dv.y + hv.z * dv.z + hv.w * dv.w;
        }
    } else {
        for (int c = 0; c < CH; c += 2) {
            float2 hv = *reinterpret_cast<const float2*>(&hp[c]);
            float2 av = *reinterpret_cast<const float2*>(&sp[c]);
            float2 dv = *reinterpret_cast<const float2*>(&dp[c]);
            s1 += hv.x * av.x + hv.y * av.y;
            s2 += hv.x * dv.x + hv.y * dv.y;
        }
    }
    asn[t] = s1;
    adn[t] = s2;
}

// ---------------------------------------------------------------------------
// Batched online-softmax aggregation. One block per node, wave = head,
// lane = channel. 32 edges per batch: lanes 0..31 compute p in parallel,
// one rescale per batch, (src,p) published via 8B LDS broadcasts.
// ---------------------------------------------------------------------------

template <int CH>
__global__ __launch_bounds__(256) void aggregate_kernel(
        const float* __restrict__ h, const float* __restrict__ asn,
        const float* __restrict__ adn, const int* __restrict__ rowptr,
        const int* __restrict__ col, const float* __restrict__ bias,
        float* __restrict__ out) {
    constexpr int HC = HEADS * CH;
    __shared__ float2 pair_lds[HEADS][32];

    const int n = blockIdx.x;
    const int hd = threadIdx.x >> 6;
    const int lane = threadIdx.x & 63;
    const int el = lane & 31;

    const int start = rowptr[n];
    const int end = rowptr[n + 1];
    const float adv = adn[(n << 2) | hd];

    float m = -INFINITY, s = 0.f, acc0 = 0.f, acc1 = 0.f;

    for (int e0 = start; e0 < end; e0 += 32) {
        int e = e0 + el;
        bool valid = (lane < 32) && (e < end);
        int srcl = n;
        float ev = -INFINITY;
        if (valid) {
            srcl = col[e];
            float t = asn[(srcl << 2) | hd] + adv;
            ev = (t > 0.f) ? t : 0.2f * t;   // leaky_relu(0.2)
        }
        // batch max (all 64 lanes; invalid hold -inf)
        float bm = ev;
#pragma unroll
        for (int o = 1; o < 64; o <<= 1) bm = fmaxf(bm, __shfl_xor(bm, o));
        float mn = fmaxf(m, bm);
        float scale = __expf(m - mn);        // first batch: exp(-inf)=0
        float p = __expf(ev - mn);           // invalid lanes -> 0
        // batch sum of p
        float ps = p;
#pragma unroll
        for (int o = 1; o < 64; o <<= 1) ps += __shfl_xor(ps, o);
        s = s * scale + ps;
        acc0 *= scale;
        acc1 *= scale;
        m = mn;

        if (lane < 32) pair_lds[hd][lane] = make_float2(__int_as_float(srcl), p);
        // same-wave LDS write->read: compiler inserts lgkmcnt, no barrier needed

        int cnt = end - e0; if (cnt > 32) cnt = 32;
        int cnt8 = (cnt + 7) & ~7;
        for (int i = 0; i < cnt8; i += 8) {
#pragma unroll
            for (int j = 0; j < 8; j += 2) {
                float2 pr0 = pair_lds[hd][i + j];
                float2 pr1 = pair_lds[hd][i + j + 1];
                int s0 = __float_as_int(pr0.x);
                int s1 = __float_as_int(pr1.x);
                float hv0 = (lane < CH) ? h[s0 * HC + hd * CH + lane] : 0.f;
                float hv1 = (lane < CH) ? h[s1 * HC + hd * CH + lane] : 0.f;
                acc0 += pr0.y * hv0;
                acc1 += pr1.y * hv1;
            }
        }
    }

    if (lane < CH) {
        float v = (acc0 + acc1) / (s + 1e-16f) + bias[hd * CH + lane];
        out[n * HC + hd * CH + lane] = fmaxf(v, 0.f);
    }
}

// ---------------------------------------------------------------------------

extern "C" void kernel_launch(void* const* d_in, const int* in_sizes, int n_in,
                              void* d_out, int out_size, void* d_ws, size_t ws_size,
                              hipStream_t stream) {
    const float* x_in = (const float*)d_in[0];
    const int* ei = (const int*)d_in[1];
    const int* src = ei;
    const int* dst = ei + N_EDGES;

    const float *W[5], *AS[5], *AD[5], *BI[5];
    for (int l = 0; l < 5; ++l) {
        W[l]  = (const float*)d_in[2 + l * 4 + 0];
        AS[l] = (const float*)d_in[2 + l * 4 + 1];
        AD[l] = (const float*)d_in[2 + l * 4 + 2];
        BI[l] = (const float*)d_in[2 + l * 4 + 3];
    }

    // workspace carve-up
    float* X    = (float*)d_ws;                 // N x 256
    float* Hb   = X + (size_t)N_NODES * 256;    // N x 256
    float* asn  = Hb + (size_t)N_NODES * 256;   // N x 4
    float* adn  = asn + (size_t)N_NODES * HEADS;
    int* rowptr = (int*)(adn + (size_t)N_NODES * HEADS);  // N+1
    int* cursor = rowptr + (N_NODES + 1);                 // N
    int* col    = cursor + N_NODES;                       // E + N

    // --- CSR build (recomputed every call; deterministic work) ---
    init_deg_kernel<<<(N_NODES + 255) / 256, 256, 0, stream>>>(cursor);
    hist_kernel<<<(N_EDGES + 255) / 256, 256, 0, stream>>>(dst, cursor);
    scan_kernel<<<1, 1024, 0, stream>>>(cursor, rowptr, cursor);
    scatter_kernel<<<(N_EDGES + N_NODES + 255) / 256, 256, 0, stream>>>(src, dst, cursor, col);

    // --- 5 GAT layers ---
    const float* cur = x_in;
    int K = 64;
    const int gemm_blocks = (N_NODES + 63) / 64;
    for (int l = 0; l < 5; ++l) {
        const int NC = (l == 4) ? 40 : 256;   // H * dout
        const int CH = (l == 4) ? 10 : 64;    // dout per head
        gemm_kernel<<<gemm_blocks, 256, 0, stream>>>(cur, W[l], Hb, N_NODES, K, NC);
        attn_coef_kernel<<<(N_NODES * HEADS + 255) / 256, 256, 0, stream>>>(
            Hb, AS[l], AD[l], asn, adn, CH);
        float* outp = (l == 4) ? (float*)d_out : X;
        if (CH == 64) {
            aggregate_kernel<64><<<N_NODES, 256, 0, stream>>>(Hb, asn, adn, rowptr, col, BI[l], outp);
        } else {
            aggregate_kernel<10><<<N_NODES, 256, 0, stream>>>(Hb, asn, adn, rowptr, col, BI[l], outp);
        }
        cur = X;
        K = 256;
    }
    (void)in_sizes; (void)n_in; (void)out_size; (void)ws_size;
}

// Round 3
// 1201.465 us; speedup vs baseline: 1.8236x; 1.2959x over previous
//
#include <hip/hip_runtime.h>
#include <hip/hip_bf16.h>
#include <math.h>

#define N_NODES 50000
#define N_PAD   50048   // 391 * 128
#define N_EDGES 800000
#define HEADS 4

typedef __attribute__((ext_vector_type(8))) short short8_t;
typedef __attribute__((ext_vector_type(4))) float f32x4;

// Exact 3-way bf16 split: v == p0 + p1 + p2 (f32 mantissa = 3 x 8 bits).
__device__ inline void split3(float v, ushort& p0, ushort& p1, ushort& p2) {
    unsigned u = __float_as_uint(v);
    p0 = (ushort)(u >> 16);
    float r = v - __uint_as_float(u & 0xffff0000u);
    unsigned u1 = __float_as_uint(r);
    p1 = (ushort)(u1 >> 16);
    float r2 = r - __uint_as_float(u1 & 0xffff0000u);
    p2 = (ushort)(__float_as_uint(r2) >> 16);
}

// ---------------------------------------------------------------------------
// CSR construction
// ---------------------------------------------------------------------------

__global__ void init_deg_kernel(int* __restrict__ deg) {
    int i = blockIdx.x * blockDim.x + threadIdx.x;
    if (i < N_NODES) deg[i] = 1;  // self-loop
}

__global__ void hist_kernel(const int* __restrict__ dst, int* __restrict__ deg) {
    int i = blockIdx.x * blockDim.x + threadIdx.x;
    if (i < N_EDGES) atomicAdd(&deg[dst[i]], 1);
}

__global__ __launch_bounds__(1024) void scan_kernel(const int* __restrict__ deg,
                                                    int* __restrict__ rowptr,
                                                    int* __restrict__ cursor) {
    __shared__ int sums[1024];
    const int t = threadIdx.x;
    const int CHUNK = (N_NODES + 1023) / 1024;
    int begin = t * CHUNK;
    int end = begin + CHUNK; if (end > N_NODES) end = N_NODES;
    if (begin > N_NODES) begin = N_NODES;

    int s = 0;
    for (int i = begin; i < end; ++i) s += deg[i];
    sums[t] = s;
    __syncthreads();
    for (int off = 1; off < 1024; off <<= 1) {
        int v = (t >= off) ? sums[t - off] : 0;
        __syncthreads();
        sums[t] += v;
        __syncthreads();
    }
    int run = (t == 0) ? 0 : sums[t - 1];
    for (int i = begin; i < end; ++i) {
        int d = deg[i];          // read BEFORE aliased write
        rowptr[i] = run;
        cursor[i] = run;
        run += d;
    }
    if (t == 1023) rowptr[N_NODES] = run;
}

__global__ void scatter_kernel(const int* __restrict__ src, const int* __restrict__ dst,
                               int* __restrict__ cursor, int* __restrict__ col) {
    int i = blockIdx.x * blockDim.x + threadIdx.x;
    if (i < N_EDGES) {
        int d = dst[i];
        int pos = atomicAdd(&cursor[d], 1);
        col[pos] = src[i];
    } else if (i < N_EDGES + N_NODES) {
        int n = i - N_EDGES;
        int pos = atomicAdd(&cursor[n], 1);
        col[pos] = n;
    }
}

// ---------------------------------------------------------------------------
// Splitters: x -> 3 planes (lda 64); W -> transposed padded planes [3][256][256]
// ---------------------------------------------------------------------------

__global__ void x_split_kernel(const float* __restrict__ x, ushort* __restrict__ pl,
                               size_t pstride) {
    int i = blockIdx.x * blockDim.x + threadIdx.x;
    if (i >= N_NODES * 64) return;
    ushort a, b, c;
    split3(x[i], a, b, c);
    pl[i] = a;
    pl[pstride + i] = b;
    pl[2 * pstride + i] = c;
}

__global__ void w_split_kernel(const float* __restrict__ W, ushort* __restrict__ wt,
                               int K, int NC) {
    int t = blockIdx.x * blockDim.x + threadIdx.x;  // 65536 = 256 cols x 256 k
    int c = t >> 8, k = t & 255;
    float v = (k < K && c < NC) ? W[k * NC + c] : 0.f;
    ushort a, b, cc;
    split3(v, a, b, cc);
    wt[t] = a;
    wt[65536 + t] = b;
    wt[131072 + t] = cc;
}

// ---------------------------------------------------------------------------
// bf16x3 MFMA GEMM: C[M x NC] = A * W  (A from planes, W from wt planes).
// Block 128x128, 4 waves (2x2 of 64x64), BK=32, mfma_f32_16x16x32_bf16.
// ---------------------------------------------------------------------------

__global__ __launch_bounds__(256) void gemm_mfma_kernel(
        const ushort* __restrict__ Apl, size_t apstride, int lda,
        const ushort* __restrict__ Wt,   // [3][256][256], zero-padded
        float* __restrict__ C, int K, int NC) {
    __shared__ ushort As[3][128][40];   // stride 80B: 16B-aligned, ~2-way banks
    __shared__ ushort Bs[3][128][40];

    const int tid = threadIdx.x;
    const int lane = tid & 63;
    const int wave = tid >> 6;
    const int wr = (wave >> 1) * 64;
    const int wc = (wave & 1) * 64;
    const int m0 = blockIdx.x * 128;
    const int n0 = blockIdx.y * 128;

    f32x4 acc[4][4];
#pragma unroll
    for (int i = 0; i < 4; ++i)
#pragma unroll
        for (int j = 0; j < 4; ++j) acc[i][j] = (f32x4){0.f, 0.f, 0.f, 0.f};

    const int row0 = tid >> 2, q0 = tid & 3;            // chunk tid
    const int row1 = (tid + 256) >> 2, q1 = q0;         // chunk tid+256

    for (int k0 = 0; k0 < K; k0 += 32) {
        if (k0) __syncthreads();
        // stage A and B tiles: per plane, 128 rows x 32 k bf16 (8KB) = 512 x 16B
#pragma unroll
        for (int p = 0; p < 3; ++p) {
            short8_t a0 = *(const short8_t*)(Apl + p * apstride + (size_t)(m0 + row0) * lda + k0 + q0 * 8);
            short8_t a1 = *(const short8_t*)(Apl + p * apstride + (size_t)(m0 + row1) * lda + k0 + q1 * 8);
            short8_t b0 = *(const short8_t*)(Wt + p * 65536 + (size_t)(n0 + row0) * 256 + k0 + q0 * 8);
            short8_t b1 = *(const short8_t*)(Wt + p * 65536 + (size_t)(n0 + row1) * 256 + k0 + q1 * 8);
            *(short8_t*)(&As[p][row0][q0 * 8]) = a0;
            *(short8_t*)(&As[p][row1][q1 * 8]) = a1;
            *(short8_t*)(&Bs[p][row0][q0 * 8]) = b0;
            *(short8_t*)(&Bs[p][row1][q1 * 8]) = b1;
        }
        __syncthreads();

        short8_t af[3][4], bf[3][4];
#pragma unroll
        for (int p = 0; p < 3; ++p)
#pragma unroll
            for (int i = 0; i < 4; ++i) {
                af[p][i] = *(const short8_t*)(&As[p][wr + i * 16 + (lane & 15)][(lane >> 4) * 8]);
                bf[p][i] = *(const short8_t*)(&Bs[p][wc + i * 16 + (lane & 15)][(lane >> 4) * 8]);
            }
#pragma unroll
        for (int i = 0; i < 4; ++i)
#pragma unroll
            for (int j = 0; j < 4; ++j) {
                f32x4 c = acc[i][j];
                c = __builtin_amdgcn_mfma_f32_16x16x32_bf16(af[0][i], bf[0][j], c, 0, 0, 0);
                c = __builtin_amdgcn_mfma_f32_16x16x32_bf16(af[0][i], bf[1][j], c, 0, 0, 0);
                c = __builtin_amdgcn_mfma_f32_16x16x32_bf16(af[1][i], bf[0][j], c, 0, 0, 0);
                c = __builtin_amdgcn_mfma_f32_16x16x32_bf16(af[0][i], bf[2][j], c, 0, 0, 0);
                c = __builtin_amdgcn_mfma_f32_16x16x32_bf16(af[1][i], bf[1][j], c, 0, 0, 0);
                c = __builtin_amdgcn_mfma_f32_16x16x32_bf16(af[2][i], bf[0][j], c, 0, 0, 0);
                acc[i][j] = c;
            }
    }

    // epilogue: C/D mapping col = lane&15, row = (lane>>4)*4 + reg
    const int rbase = m0 + wr + (lane >> 4) * 4;
    const int cbase = n0 + wc + (lane & 15);
#pragma unroll
    for (int i = 0; i < 4; ++i)
#pragma unroll
        for (int j = 0; j < 4; ++j) {
            int gcol = cbase + j * 16;
            if (gcol >= NC) continue;
#pragma unroll
            for (int r4 = 0; r4 < 4; ++r4) {
                int grow = rbase + i * 16 + r4;
                if (grow < N_NODES) C[(size_t)grow * NC + gcol] = acc[i][j][r4];
            }
        }
}

// ---------------------------------------------------------------------------
// Attention coefficients
// ---------------------------------------------------------------------------

__global__ void attn_coef_kernel(const float* __restrict__ h,
                                 const float* __restrict__ a_s,
                                 const float* __restrict__ a_d,
                                 float* __restrict__ asn, float* __restrict__ adn,
                                 int CH) {
    int t = blockIdx.x * blockDim.x + threadIdx.x;
    if (t >= N_NODES * HEADS) return;
    int n = t >> 2;
    int hd = t & 3;
    const float* hp = h + (size_t)n * HEADS * CH + hd * CH;
    const float* sp = a_s + hd * CH;
    const float* dp = a_d + hd * CH;
    float s1 = 0.f, s2 = 0.f;
    if ((CH & 3) == 0) {
        for (int c = 0; c < CH; c += 4) {
            float4 hv = *reinterpret_cast<const float4*>(&hp[c]);
            float4 av = *reinterpret_cast<const float4*>(&sp[c]);
            float4 dv = *reinterpret_cast<const float4*>(&dp[c]);
            s1 += hv.x * av.x + hv.y * av.y + hv.z * av.z + hv.w * av.w;
            s2 += hv.x * dv.x + hv.y * dv.y + hv.z * dv.z + hv.w * dv.w;
        }
    } else {
        for (int c = 0; c < CH; c += 2) {
            float2 hv = *reinterpret_cast<const float2*>(&hp[c]);
            float2 av = *reinterpret_cast<const float2*>(&sp[c]);
            float2 dv = *reinterpret_cast<const float2*>(&dp[c]);
            s1 += hv.x * av.x + hv.y * av.y;
            s2 += hv.x * dv.x + hv.y * dv.y;
        }
    }
    asn[t] = s1;
    adn[t] = s2;
}

// ---------------------------------------------------------------------------
// Batched online-softmax aggregation; EMIT=1 -> write 3 bf16 planes (exact split)
// ---------------------------------------------------------------------------

template <int CH, int EMIT>
__global__ __launch_bounds__(256) void aggregate_kernel(
        const float* __restrict__ h, const float* __restrict__ asn,
        const float* __restrict__ adn, const int* __restrict__ rowptr,
        const int* __restrict__ col, const float* __restrict__ bias,
        ushort* __restrict__ pl, size_t pstride, float* __restrict__ out) {
    constexpr int HC = HEADS * CH;
    __shared__ float2 pair_lds[HEADS][32];

    const int n = blockIdx.x;
    const int hd = threadIdx.x >> 6;
    const int lane = threadIdx.x & 63;
    const int el = lane & 31;

    const int start = rowptr[n];
    const int end = rowptr[n + 1];
    const float adv = adn[(n << 2) | hd];

    float m = -INFINITY, s = 0.f, acc0 = 0.f, acc1 = 0.f;

    for (int e0 = start; e0 < end; e0 += 32) {
        int e = e0 + el;
        bool valid = (lane < 32) && (e < end);
        int srcl = n;
        float ev = -INFINITY;
        if (valid) {
            srcl = col[e];
            float t = asn[(srcl << 2) | hd] + adv;
            ev = (t > 0.f) ? t : 0.2f * t;
        }
        float bm = ev;
#pragma unroll
        for (int o = 1; o < 64; o <<= 1) bm = fmaxf(bm, __shfl_xor(bm, o));
        float mn = fmaxf(m, bm);
        float scale = __expf(m - mn);
        float p = __expf(ev - mn);
        float ps = p;
#pragma unroll
        for (int o = 1; o < 64; o <<= 1) ps += __shfl_xor(ps, o);
        s = s * scale + ps;
        acc0 *= scale;
        acc1 *= scale;
        m = mn;

        if (lane < 32) pair_lds[hd][lane] = make_float2(__int_as_float(srcl), p);

        int cnt = end - e0; if (cnt > 32) cnt = 32;
        int cnt8 = (cnt + 7) & ~7;
        for (int i = 0; i < cnt8; i += 8) {
#pragma unroll
            for (int j = 0; j < 8; j += 2) {
                float2 pr0 = pair_lds[hd][i + j];
                float2 pr1 = pair_lds[hd][i + j + 1];
                int s0 = __float_as_int(pr0.x);
                int s1 = __float_as_int(pr1.x);
                float hv0 = (lane < CH) ? h[s0 * HC + hd * CH + lane] : 0.f;
                float hv1 = (lane < CH) ? h[s1 * HC + hd * CH + lane] : 0.f;
                acc0 += pr0.y * hv0;
                acc1 += pr1.y * hv1;
            }
        }
    }

    if (lane < CH) {
        float v = (acc0 + acc1) / (s + 1e-16f) + bias[hd * CH + lane];
        v = fmaxf(v, 0.f);
        if (EMIT) {
            ushort a, b, c;
            split3(v, a, b, c);
            size_t off = (size_t)n * HC + hd * CH + lane;
            pl[off] = a;
            pl[pstride + off] = b;
            pl[2 * pstride + off] = c;
        } else {
            out[n * HC + hd * CH + lane] = v;
        }
    }
}

// ---------------------------------------------------------------------------

extern "C" void kernel_launch(void* const* d_in, const int* in_sizes, int n_in,
                              void* d_out, int out_size, void* d_ws, size_t ws_size,
                              hipStream_t stream) {
    const float* x_in = (const float*)d_in[0];
    const int* ei = (const int*)d_in[1];
    const int* src = ei;
    const int* dst = ei + N_EDGES;

    const float *W[5], *AS[5], *AD[5], *BI[5];
    for (int l = 0; l < 5; ++l) {
        W[l]  = (const float*)d_in[2 + l * 4 + 0];
        AS[l] = (const float*)d_in[2 + l * 4 + 1];
        AD[l] = (const float*)d_in[2 + l * 4 + 2];
        BI[l] = (const float*)d_in[2 + l * 4 + 3];
    }

    // workspace carve-up
    const size_t PSTRIDE = (size_t)N_PAD * 256;           // elements per plane
    ushort* planes = (ushort*)d_ws;                       // 3 planes (bf16)
    float* Hb   = (float*)(planes + 3 * PSTRIDE);         // N x 256 f32
    float* asn  = Hb + (size_t)N_NODES * 256;
    float* adn  = asn + (size_t)N_NODES * HEADS;
    int* rowptr = (int*)(adn + (size_t)N_NODES * HEADS);  // N+1
    int* cursor = rowptr + (N_NODES + 1);
    int* col    = cursor + N_NODES;                       // E + N
    ushort* wt  = (ushort*)(((uintptr_t)(col + N_EDGES + N_NODES) + 15) & ~(uintptr_t)15);

    // --- CSR build ---
    init_deg_kernel<<<(N_NODES + 255) / 256, 256, 0, stream>>>(cursor);
    hist_kernel<<<(N_EDGES + 255) / 256, 256, 0, stream>>>(dst, cursor);
    scan_kernel<<<1, 1024, 0, stream>>>(cursor, rowptr, cursor);
    scatter_kernel<<<(N_EDGES + N_NODES + 255) / 256, 256, 0, stream>>>(src, dst, cursor, col);

    // --- weight & input splits ---
    for (int l = 0; l < 5; ++l) {
        int Kl = (l == 0) ? 64 : 256;
        int NCl = (l == 4) ? 40 : 256;
        w_split_kernel<<<256, 256, 0, stream>>>(W[l], wt + (size_t)l * 3 * 65536, Kl, NCl);
    }
    x_split_kernel<<<(N_NODES * 64 + 255) / 256, 256, 0, stream>>>(x_in, planes, PSTRIDE);

    // --- 5 GAT layers ---
    int lda = 64;
    for (int l = 0; l < 5; ++l) {
        const int K = (l == 0) ? 64 : 256;
        const int NC = (l == 4) ? 40 : 256;
        const int CH = NC / HEADS;
        dim3 ggrid(N_PAD / 128, (NC + 127) / 128);
        gemm_mfma_kernel<<<ggrid, 256, 0, stream>>>(planes, PSTRIDE, lda,
                                                    wt + (size_t)l * 3 * 65536, Hb, K, NC);
        attn_coef_kernel<<<(N_NODES * HEADS + 255) / 256, 256, 0, stream>>>(
            Hb, AS[l], AD[l], asn, adn, CH);
        if (l < 4) {
            aggregate_kernel<64, 1><<<N_NODES, 256, 0, stream>>>(
                Hb, asn, adn, rowptr, col, BI[l], planes, PSTRIDE, nullptr);
        } else {
            aggregate_kernel<10, 0><<<N_NODES, 256, 0, stream>>>(
                Hb, asn, adn, rowptr, col, BI[l], nullptr, 0, (float*)d_out);
        }
        lda = 256;
    }
    (void)in_sizes; (void)n_in; (void)out_size; (void)ws_size;
}

// Round 4
// 1141.912 us; speedup vs baseline: 1.9187x; 1.0522x over previous
//
#include <hip/hip_runtime.h>
#include <hip/hip_bf16.h>
#include <math.h>

#define N_NODES 50000
#define N_PAD   50048   // 391 * 128
#define N_EDGES 800000
#define HEADS 4

typedef __attribute__((ext_vector_type(8))) short short8_t;
typedef __attribute__((ext_vector_type(4))) float f32x4;

// Exact 3-way bf16 split: v == p0 + p1 + p2 (f32 mantissa = 3 x 8 bits).
__device__ inline void split3(float v, ushort& p0, ushort& p1, ushort& p2) {
    unsigned u = __float_as_uint(v);
    p0 = (ushort)(u >> 16);
    float r = v - __uint_as_float(u & 0xffff0000u);
    unsigned u1 = __float_as_uint(r);
    p1 = (ushort)(u1 >> 16);
    float r2 = r - __uint_as_float(u1 & 0xffff0000u);
    p2 = (ushort)(__float_as_uint(r2) >> 16);
}

// ---------------------------------------------------------------------------
// CSR construction
// ---------------------------------------------------------------------------

__global__ void init_deg_kernel(int* __restrict__ deg) {
    int i = blockIdx.x * blockDim.x + threadIdx.x;
    if (i < N_NODES) deg[i] = 1;  // self-loop
}

__global__ void hist_kernel(const int* __restrict__ dst, int* __restrict__ deg) {
    int i = blockIdx.x * blockDim.x + threadIdx.x;
    if (i < N_EDGES) atomicAdd(&deg[dst[i]], 1);
}

__global__ __launch_bounds__(1024) void scan_kernel(const int* __restrict__ deg,
                                                    int* __restrict__ rowptr,
                                                    int* __restrict__ cursor) {
    __shared__ int sums[1024];
    const int t = threadIdx.x;
    const int CHUNK = (N_NODES + 1023) / 1024;
    int begin = t * CHUNK;
    int end = begin + CHUNK; if (end > N_NODES) end = N_NODES;
    if (begin > N_NODES) begin = N_NODES;

    int s = 0;
    for (int i = begin; i < end; ++i) s += deg[i];
    sums[t] = s;
    __syncthreads();
    for (int off = 1; off < 1024; off <<= 1) {
        int v = (t >= off) ? sums[t - off] : 0;
        __syncthreads();
        sums[t] += v;
        __syncthreads();
    }
    int run = (t == 0) ? 0 : sums[t - 1];
    for (int i = begin; i < end; ++i) {
        int d = deg[i];          // read BEFORE aliased write
        rowptr[i] = run;
        cursor[i] = run;
        run += d;
    }
    if (t == 1023) rowptr[N_NODES] = run;
}

__global__ void scatter_kernel(const int* __restrict__ src, const int* __restrict__ dst,
                               int* __restrict__ cursor, int* __restrict__ col) {
    int i = blockIdx.x * blockDim.x + threadIdx.x;
    if (i < N_EDGES) {
        int d = dst[i];
        int pos = atomicAdd(&cursor[d], 1);
        col[pos] = src[i];
    } else if (i < N_EDGES + N_NODES) {
        int n = i - N_EDGES;
        int pos = atomicAdd(&cursor[n], 1);
        col[pos] = n;
    }
}

// ---------------------------------------------------------------------------
// Splitters
// ---------------------------------------------------------------------------

__global__ void x_split_kernel(const float* __restrict__ x, ushort* __restrict__ pl,
                               size_t pstride) {
    int i = blockIdx.x * blockDim.x + threadIdx.x;
    if (i >= N_NODES * 64) return;
    ushort a, b, c;
    split3(x[i], a, b, c);
    pl[i] = a;
    pl[pstride + i] = b;
    pl[2 * pstride + i] = c;
}

__global__ void w_split_kernel(const float* __restrict__ W, ushort* __restrict__ wt,
                               int K, int NC) {
    int t = blockIdx.x * blockDim.x + threadIdx.x;  // 65536 = 256 cols x 256 k
    int c = t >> 8, k = t & 255;
    float v = (k < K && c < NC) ? W[k * NC + c] : 0.f;
    ushort a, b, cc;
    split3(v, a, b, cc);
    wt[t] = a;
    wt[65536 + t] = b;
    wt[131072 + t] = cc;
}

// ---------------------------------------------------------------------------
// bf16x3 MFMA GEMM, reg-prefetch pipelined; optional fused attn-coef epilogue
// (CH==64 layers: each 64-col wave quarter == exactly one head).
// Block 128x128, 4 waves (2x2 of 64x64), BK=32, mfma_f32_16x16x32_bf16.
// ---------------------------------------------------------------------------

template <int FUSE_ATTN>
__global__ __launch_bounds__(256) void gemm_mfma_kernel(
        const ushort* __restrict__ Apl, size_t apstride, int lda,
        const ushort* __restrict__ Wt,   // [3][256][256], zero-padded
        float* __restrict__ C, int K, int NC,
        const float* __restrict__ as_flat, const float* __restrict__ ad_flat,
        float* __restrict__ asn, float* __restrict__ adn) {
    __shared__ ushort As[3][128][40];   // stride 80B: 16B-aligned, even bank spread
    __shared__ ushort Bs[3][128][40];

    const int tid = threadIdx.x;
    const int lane = tid & 63;
    const int wave = tid >> 6;
    const int wr = (wave >> 1) * 64;
    const int wc = (wave & 1) * 64;
    const int m0 = blockIdx.x * 128;
    const int n0 = blockIdx.y * 128;

    f32x4 acc[4][4];
#pragma unroll
    for (int i = 0; i < 4; ++i)
#pragma unroll
        for (int j = 0; j < 4; ++j) acc[i][j] = (f32x4){0.f, 0.f, 0.f, 0.f};

    const int row0 = tid >> 2, q = tid & 3;
    const int row1 = row0 + 64;

    const ushort* aptr0 = Apl + (size_t)(m0 + row0) * lda + q * 8;
    const ushort* aptr1 = Apl + (size_t)(m0 + row1) * lda + q * 8;
    const ushort* bptr0 = Wt + (size_t)(n0 + row0) * 256 + q * 8;
    const ushort* bptr1 = Wt + (size_t)(n0 + row1) * 256 + q * 8;

    short8_t pa[3][2], pb[3][2];
    // prefetch k0 = 0
#pragma unroll
    for (int p = 0; p < 3; ++p) {
        pa[p][0] = *(const short8_t*)(aptr0 + p * apstride);
        pa[p][1] = *(const short8_t*)(aptr1 + p * apstride);
        pb[p][0] = *(const short8_t*)(bptr0 + p * 65536);
        pb[p][1] = *(const short8_t*)(bptr1 + p * 65536);
    }

    for (int k0 = 0; k0 < K; k0 += 32) {
        if (k0) __syncthreads();   // prev-iter LDS readers done
#pragma unroll
        for (int p = 0; p < 3; ++p) {
            *(short8_t*)(&As[p][row0][q * 8]) = pa[p][0];
            *(short8_t*)(&As[p][row1][q * 8]) = pa[p][1];
            *(short8_t*)(&Bs[p][row0][q * 8]) = pb[p][0];
            *(short8_t*)(&Bs[p][row1][q * 8]) = pb[p][1];
        }
        __syncthreads();

        // issue next-tile global loads early: latency hides under ds_read+MFMA
        if (k0 + 32 < K) {
            int kn = k0 + 32;
#pragma unroll
            for (int p = 0; p < 3; ++p) {
                pa[p][0] = *(const short8_t*)(aptr0 + p * apstride + kn);
                pa[p][1] = *(const short8_t*)(aptr1 + p * apstride + kn);
                pb[p][0] = *(const short8_t*)(bptr0 + p * 65536 + kn);
                pb[p][1] = *(const short8_t*)(bptr1 + p * 65536 + kn);
            }
        }

        short8_t bf[3][4];
#pragma unroll
        for (int p = 0; p < 3; ++p)
#pragma unroll
            for (int j = 0; j < 4; ++j)
                bf[p][j] = *(const short8_t*)(&Bs[p][wc + j * 16 + (lane & 15)][(lane >> 4) * 8]);

#pragma unroll
        for (int i = 0; i < 4; ++i) {
            short8_t af0 = *(const short8_t*)(&As[0][wr + i * 16 + (lane & 15)][(lane >> 4) * 8]);
            short8_t af1 = *(const short8_t*)(&As[1][wr + i * 16 + (lane & 15)][(lane >> 4) * 8]);
            short8_t af2 = *(const short8_t*)(&As[2][wr + i * 16 + (lane & 15)][(lane >> 4) * 8]);
#pragma unroll
            for (int j = 0; j < 4; ++j) {
                f32x4 c = acc[i][j];
                c = __builtin_amdgcn_mfma_f32_16x16x32_bf16(af0, bf[0][j], c, 0, 0, 0);
                c = __builtin_amdgcn_mfma_f32_16x16x32_bf16(af0, bf[1][j], c, 0, 0, 0);
                c = __builtin_amdgcn_mfma_f32_16x16x32_bf16(af1, bf[0][j], c, 0, 0, 0);
                c = __builtin_amdgcn_mfma_f32_16x16x32_bf16(af0, bf[2][j], c, 0, 0, 0);
                c = __builtin_amdgcn_mfma_f32_16x16x32_bf16(af1, bf[1][j], c, 0, 0, 0);
                c = __builtin_amdgcn_mfma_f32_16x16x32_bf16(af2, bf[0][j], c, 0, 0, 0);
                acc[i][j] = c;
            }
        }
    }

    // epilogue: C/D mapping col = lane&15, row = (lane>>4)*4 + reg
    const int rbase = m0 + wr + (lane >> 4) * 4;
    const int cbase = n0 + wc + (lane & 15);
#pragma unroll
    for (int i = 0; i < 4; ++i)
#pragma unroll
        for (int j = 0; j < 4; ++j) {
            int gcol = cbase + j * 16;
            if (gcol >= NC) continue;
#pragma unroll
            for (int r4 = 0; r4 < 4; ++r4) {
                int grow = rbase + i * 16 + r4;
                if (grow < N_NODES) C[(size_t)grow * NC + gcol] = acc[i][j][r4];
            }
        }

    if (FUSE_ATTN) {
        // this wave's 64 cols == head (n0+wc)>>6 (CH=64)
        const int hd_out = (n0 + wc) >> 6;
        float as_v[4], ad_v[4];
#pragma unroll
        for (int j = 0; j < 4; ++j) {
            int gc = cbase + j * 16;
            as_v[j] = as_flat[gc];
            ad_v[j] = ad_flat[gc];
        }
#pragma unroll
        for (int i = 0; i < 4; ++i)
#pragma unroll
            for (int r4 = 0; r4 < 4; ++r4) {
                float ps = 0.f, pd = 0.f;
#pragma unroll
                for (int j = 0; j < 4; ++j) {
                    float v = acc[i][j][r4];
                    ps += v * as_v[j];
                    pd += v * ad_v[j];
                }
                // reduce over the 16 lanes (lane&15) sharing this row
#pragma unroll
                for (int o = 1; o < 16; o <<= 1) {
                    ps += __shfl_xor(ps, o);
                    pd += __shfl_xor(pd, o);
                }
                if ((lane & 15) == 0) {
                    int grow = rbase + i * 16 + r4;
                    if (grow < N_NODES) {
                        asn[grow * 4 + hd_out] = ps;
                        adn[grow * 4 + hd_out] = pd;
                    }
                }
            }
    }
}

// ---------------------------------------------------------------------------
// Standalone attention coefficients (layer 4 only, CH=10)
// ---------------------------------------------------------------------------

__global__ void attn_coef_kernel(const float* __restrict__ h,
                                 const float* __restrict__ a_s,
                                 const float* __restrict__ a_d,
                                 float* __restrict__ asn, float* __restrict__ adn,
                                 int CH) {
    int t = blockIdx.x * blockDim.x + threadIdx.x;
    if (t >= N_NODES * HEADS) return;
    int n = t >> 2;
    int hd = t & 3;
    const float* hp = h + (size_t)n * HEADS * CH + hd * CH;
    const float* sp = a_s + hd * CH;
    const float* dp = a_d + hd * CH;
    float s1 = 0.f, s2 = 0.f;
    for (int c = 0; c < CH; c += 2) {
        float2 hv = *reinterpret_cast<const float2*>(&hp[c]);
        float2 av = *reinterpret_cast<const float2*>(&sp[c]);
        float2 dv = *reinterpret_cast<const float2*>(&dp[c]);
        s1 += hv.x * av.x + hv.y * av.y;
        s2 += hv.x * dv.x + hv.y * dv.y;
    }
    asn[t] = s1;
    adn[t] = s2;
}

// ---------------------------------------------------------------------------
// Batched online-softmax aggregation; EMIT=1 -> write 3 bf16 planes (exact split)
// ---------------------------------------------------------------------------

template <int CH, int EMIT>
__global__ __launch_bounds__(256) void aggregate_kernel(
        const float* __restrict__ h, const float* __restrict__ asn,
        const float* __restrict__ adn, const int* __restrict__ rowptr,
        const int* __restrict__ col, const float* __restrict__ bias,
        ushort* __restrict__ pl, size_t pstride, float* __restrict__ out) {
    constexpr int HC = HEADS * CH;
    __shared__ float2 pair_lds[HEADS][32];

    const int n = blockIdx.x;
    const int hd = threadIdx.x >> 6;
    const int lane = threadIdx.x & 63;
    const int el = lane & 31;

    const int start = rowptr[n];
    const int end = rowptr[n + 1];
    const float adv = adn[(n << 2) | hd];

    float m = -INFINITY, s = 0.f, acc0 = 0.f, acc1 = 0.f;

    for (int e0 = start; e0 < end; e0 += 32) {
        int e = e0 + el;
        bool valid = (lane < 32) && (e < end);
        int srcl = n;
        float ev = -INFINITY;
        if (valid) {
            srcl = col[e];
            float t = asn[(srcl << 2) | hd] + adv;
            ev = (t > 0.f) ? t : 0.2f * t;
        }
        float bm = ev;
#pragma unroll
        for (int o = 1; o < 64; o <<= 1) bm = fmaxf(bm, __shfl_xor(bm, o));
        float mn = fmaxf(m, bm);
        float scale = __expf(m - mn);
        float p = __expf(ev - mn);
        float ps = p;
#pragma unroll
        for (int o = 1; o < 64; o <<= 1) ps += __shfl_xor(ps, o);
        s = s * scale + ps;
        acc0 *= scale;
        acc1 *= scale;
        m = mn;

        if (lane < 32) pair_lds[hd][lane] = make_float2(__int_as_float(srcl), p);

        int cnt = end - e0; if (cnt > 32) cnt = 32;
        int cnt8 = (cnt + 7) & ~7;
        for (int i = 0; i < cnt8; i += 8) {
#pragma unroll
            for (int j = 0; j < 8; j += 2) {
                float2 pr0 = pair_lds[hd][i + j];
                float2 pr1 = pair_lds[hd][i + j + 1];
                int s0 = __float_as_int(pr0.x);
                int s1 = __float_as_int(pr1.x);
                float hv0 = (lane < CH) ? h[s0 * HC + hd * CH + lane] : 0.f;
                float hv1 = (lane < CH) ? h[s1 * HC + hd * CH + lane] : 0.f;
                acc0 += pr0.y * hv0;
                acc1 += pr1.y * hv1;
            }
        }
    }

    if (lane < CH) {
        float v = (acc0 + acc1) / (s + 1e-16f) + bias[hd * CH + lane];
        v = fmaxf(v, 0.f);
        if (EMIT) {
            ushort a, b, c;
            split3(v, a, b, c);
            size_t off = (size_t)n * HC + hd * CH + lane;
            pl[off] = a;
            pl[pstride + off] = b;
            pl[2 * pstride + off] = c;
        } else {
            out[n * HC + hd * CH + lane] = v;
        }
    }
}

// ---------------------------------------------------------------------------

extern "C" void kernel_launch(void* const* d_in, const int* in_sizes, int n_in,
                              void* d_out, int out_size, void* d_ws, size_t ws_size,
                              hipStream_t stream) {
    const float* x_in = (const float*)d_in[0];
    const int* ei = (const int*)d_in[1];
    const int* src = ei;
    const int* dst = ei + N_EDGES;

    const float *W[5], *AS[5], *AD[5], *BI[5];
    for (int l = 0; l < 5; ++l) {
        W[l]  = (const float*)d_in[2 + l * 4 + 0];
        AS[l] = (const float*)d_in[2 + l * 4 + 1];
        AD[l] = (const float*)d_in[2 + l * 4 + 2];
        BI[l] = (const float*)d_in[2 + l * 4 + 3];
    }

    // workspace carve-up
    const size_t PSTRIDE = (size_t)N_PAD * 256;           // elements per plane
    ushort* planes = (ushort*)d_ws;                       // 3 planes (bf16)
    float* Hb   = (float*)(planes + 3 * PSTRIDE);         // N x 256 f32
    float* asn  = Hb + (size_t)N_NODES * 256;
    float* adn  = asn + (size_t)N_NODES * HEADS;
    int* rowptr = (int*)(adn + (size_t)N_NODES * HEADS);  // N+1
    int* cursor = rowptr + (N_NODES + 1);
    int* col    = cursor + N_NODES;                       // E + N
    ushort* wt  = (ushort*)(((uintptr_t)(col + N_EDGES + N_NODES) + 15) & ~(uintptr_t)15);

    // --- CSR build ---
    init_deg_kernel<<<(N_NODES + 255) / 256, 256, 0, stream>>>(cursor);
    hist_kernel<<<(N_EDGES + 255) / 256, 256, 0, stream>>>(dst, cursor);
    scan_kernel<<<1, 1024, 0, stream>>>(cursor, rowptr, cursor);
    scatter_kernel<<<(N_EDGES + N_NODES + 255) / 256, 256, 0, stream>>>(src, dst, cursor, col);

    // --- weight & input splits ---
    for (int l = 0; l < 5; ++l) {
        int Kl = (l == 0) ? 64 : 256;
        int NCl = (l == 4) ? 40 : 256;
        w_split_kernel<<<256, 256, 0, stream>>>(W[l], wt + (size_t)l * 3 * 65536, Kl, NCl);
    }
    x_split_kernel<<<(N_NODES * 64 + 255) / 256, 256, 0, stream>>>(x_in, planes, PSTRIDE);

    // --- 5 GAT layers ---
    int lda = 64;
    for (int l = 0; l < 5; ++l) {
        const int K = (l == 0) ? 64 : 256;
        const int NC = (l == 4) ? 40 : 256;
        dim3 ggrid(N_PAD / 128, (NC + 127) / 128);
        if (l < 4) {
            gemm_mfma_kernel<1><<<ggrid, 256, 0, stream>>>(
                planes, PSTRIDE, lda, wt + (size_t)l * 3 * 65536, Hb, K, NC,
                AS[l], AD[l], asn, adn);
            aggregate_kernel<64, 1><<<N_NODES, 256, 0, stream>>>(
                Hb, asn, adn, rowptr, col, BI[l], planes, PSTRIDE, nullptr);
        } else {
            gemm_mfma_kernel<0><<<ggrid, 256, 0, stream>>>(
                planes, PSTRIDE, lda, wt + (size_t)l * 3 * 65536, Hb, K, NC,
                AS[l], AD[l], asn, adn);
            attn_coef_kernel<<<(N_NODES * HEADS + 255) / 256, 256, 0, stream>>>(
                Hb, AS[l], AD[l], asn, adn, 10);
            aggregate_kernel<10, 0><<<N_NODES, 256, 0, stream>>>(
                Hb, asn, adn, rowptr, col, BI[l], nullptr, 0, (float*)d_out);
        }
        lda = 256;
    }
    (void)in_sizes; (void)n_in; (void)out_size; (void)ws_size;
}